// Round 2
// baseline (5128.426 us; speedup 1.0000x reference)
//
#include <hip/hip_runtime.h>
#include <hip/hip_bf16.h>
#include <stdint.h>

#define B_  32
#define E_  512
#define WN  2048
#define D_  1024

__device__ int g_mask_is_int;   // 1 if mask buffer is int32 per element, 0 if uint8

__device__ __forceinline__ unsigned short f2bf(float f) {
  unsigned int u = __float_as_uint(f);
  u += 0x7fffu + ((u >> 16) & 1u);   // round-to-nearest-even
  return (unsigned short)(u >> 16);
}
__device__ __forceinline__ float bf2f(unsigned short s) {
  return __uint_as_float(((unsigned int)s) << 16);
}

// ---------------------------------------------------------------------------
// K0: detect mask dtype. int32 0/1 data => bytes at offset %4 != 0 are all 0.
// ---------------------------------------------------------------------------
__global__ void k_detect(const unsigned char* __restrict__ m) {
  if (threadIdx.x == 0) {
    int nz = 0;
    for (int i = 0; i < 1024; ++i)
      if ((i & 3) && m[i]) nz++;
    g_mask_is_int = (nz == 0) ? 1 : 0;
  }
}

// ---------------------------------------------------------------------------
// K1: proj = tanh(ems @ W^T + bias) -> out (f32), out used as scratch.
// M=16384, N=1024, K=1024. 128x128 tile, BK=32, 256 thr, 8x8 per thread.
// ---------------------------------------------------------------------------
__global__ __launch_bounds__(256, 4) void k_proj(const float* __restrict__ A,
                                                 const float* __restrict__ W,
                                                 const float* __restrict__ bias,
                                                 float* __restrict__ out) {
  __shared__ float As[32][132];
  __shared__ float Bs[32][132];
  const int t = threadIdx.x;
  const int m0 = blockIdx.x * 128;
  const int n0 = blockIdx.y * 128;
  const int tm = t >> 4;        // 0..15
  const int tn = t & 15;        // 0..15
  const int lrow = t >> 1;      // 0..127
  const int lk = (t & 1) * 16;  // 0 or 16

  float acc[8][8];
#pragma unroll
  for (int i = 0; i < 8; ++i)
#pragma unroll
    for (int j = 0; j < 8; ++j) acc[i][j] = 0.0f;

  const float* Arow = A + (size_t)(m0 + lrow) * D_ + lk;
  const float* Wrow = W + (size_t)(n0 + lrow) * D_ + lk;

  for (int k0 = 0; k0 < D_; k0 += 32) {
    __syncthreads();
#pragma unroll
    for (int j = 0; j < 4; ++j) {
      const float4 va = *(const float4*)(Arow + k0 + j * 4);
      As[lk + j * 4 + 0][lrow] = va.x;
      As[lk + j * 4 + 1][lrow] = va.y;
      As[lk + j * 4 + 2][lrow] = va.z;
      As[lk + j * 4 + 3][lrow] = va.w;
      const float4 vb = *(const float4*)(Wrow + k0 + j * 4);
      Bs[lk + j * 4 + 0][lrow] = vb.x;
      Bs[lk + j * 4 + 1][lrow] = vb.y;
      Bs[lk + j * 4 + 2][lrow] = vb.z;
      Bs[lk + j * 4 + 3][lrow] = vb.w;
    }
    __syncthreads();
#pragma unroll 8
    for (int k = 0; k < 32; ++k) {
      float a[8], b[8];
      *(float4*)(a + 0) = *(const float4*)&As[k][tm * 4];
      *(float4*)(a + 4) = *(const float4*)&As[k][tm * 4 + 64];
      *(float4*)(b + 0) = *(const float4*)&Bs[k][tn * 4];
      *(float4*)(b + 4) = *(const float4*)&Bs[k][tn * 4 + 64];
#pragma unroll
      for (int i = 0; i < 8; ++i)
#pragma unroll
        for (int j = 0; j < 8; ++j) acc[i][j] = fmaf(a[i], b[j], acc[i][j]);
    }
  }

  float bn[8];
#pragma unroll
  for (int j = 0; j < 8; ++j) bn[j] = bias[n0 + tn * 4 + (j & 3) + (j >> 2) * 64];
#pragma unroll
  for (int i = 0; i < 8; ++i) {
    const int m = m0 + tm * 4 + (i & 3) + (i >> 2) * 64;
    float4 v0, v1;
    v0.x = tanhf(acc[i][0] + bn[0]);
    v0.y = tanhf(acc[i][1] + bn[1]);
    v0.z = tanhf(acc[i][2] + bn[2]);
    v0.w = tanhf(acc[i][3] + bn[3]);
    v1.x = tanhf(acc[i][4] + bn[4]);
    v1.y = tanhf(acc[i][5] + bn[5]);
    v1.z = tanhf(acc[i][6] + bn[6]);
    v1.w = tanhf(acc[i][7] + bn[7]);
    *(float4*)(out + (size_t)m * D_ + n0 + tn * 4) = v0;
    *(float4*)(out + (size_t)m * D_ + n0 + tn * 4 + 64) = v1;
  }
}

// ---------------------------------------------------------------------------
// K2: per (b, 16-row e-tile): scores = proj @ words^T (full f32), mask,
// exact softmax, write att (bf16) back into the same d_out rows.
// Thread t: eg = t>>5 owns e = eg*2 + i (i<2); ng = t&31.
// Scores per thread: s[2][64], n_global = nb*256 + q*128 + ng*4 + j.
// ---------------------------------------------------------------------------
__global__ __launch_bounds__(256) void k_scores(const float* __restrict__ words,
                                                const void* __restrict__ mask,
                                                float* __restrict__ pa) {
  __shared__ float Pt[1024][18];   // proj transposed [d][e], 72 KB
  __shared__ float Ws[64][268];    // words chunk [d][n], 67 KB
  const int t = threadIdx.x;
  const int b = blockIdx.x >> 5;
  const int et = blockIdx.x & 31;
  const int e0 = et * 16;
  const int eg = t >> 5;   // 0..7
  const int ng = t & 31;   // 0..31
  const int mask_is_int = g_mask_is_int;
  const float* wbase = words + (size_t)b * WN * D_;

  // Load 16 proj rows -> Pt (transposed). Read BEFORE any write to these rows.
  {
    const int row = t >> 4;        // 0..15
    const int dj = (t & 15) * 4;   // 0..60
    const float* pr = pa + (size_t)(b * E_ + e0 + row) * D_;
#pragma unroll
    for (int r = 0; r < 16; ++r) {
      const float4 v = *(const float4*)(pr + dj + r * 64);
      Pt[dj + r * 64 + 0][row] = v.x;
      Pt[dj + r * 64 + 1][row] = v.y;
      Pt[dj + r * 64 + 2][row] = v.z;
      Pt[dj + r * 64 + 3][row] = v.w;
    }
  }

  float s[2][64];
#pragma unroll
  for (int i = 0; i < 2; ++i)
#pragma unroll
    for (int u = 0; u < 64; ++u) s[i][u] = 0.0f;

  const int nl = t >> 3;        // 0..31
  const int d4 = (t & 7) * 4;   // 0..28

  for (int dk = 0; dk < D_; dk += 64) {
#pragma unroll
    for (int nb = 0; nb < 8; ++nb) {
      __syncthreads();
      // stage words[n-slice nb][dk..dk+64) transposed into Ws[d][n]
#pragma unroll
      for (int r = 0; r < 8; ++r) {
#pragma unroll
        for (int h = 0; h < 2; ++h) {
          const int n = nl + r * 32;
          const int d = d4 + h * 32;
          const float4 v = *(const float4*)(wbase + (size_t)(nb * 256 + n) * D_ + dk + d);
          Ws[d + 0][n] = v.x;
          Ws[d + 1][n] = v.y;
          Ws[d + 2][n] = v.z;
          Ws[d + 3][n] = v.w;
        }
      }
      __syncthreads();
#pragma unroll 2
      for (int k = 0; k < 64; ++k) {
        const float2 a = *(const float2*)&Pt[dk + k][eg * 2];
        const float4 b0 = *(const float4*)&Ws[k][ng * 4];
        const float4 b1 = *(const float4*)&Ws[k][128 + ng * 4];
        const float aa[2] = {a.x, a.y};
        const float bb[8] = {b0.x, b0.y, b0.z, b0.w, b1.x, b1.y, b1.z, b1.w};
#pragma unroll
        for (int i = 0; i < 2; ++i)
#pragma unroll
          for (int u = 0; u < 8; ++u)
            s[i][nb * 8 + u] = fmaf(aa[i], bb[u], s[i][nb * 8 + u]);
      }
    }
  }

  // mask + softmax (exact, full row of 2048) + store att as bf16
#pragma unroll
  for (int i = 0; i < 2; ++i) {
    const int e = e0 + eg * 2 + i;
#pragma unroll
    for (int nb = 0; nb < 8; ++nb)
#pragma unroll
      for (int q = 0; q < 2; ++q) {
        const size_t moff = (size_t)(b * E_ + e) * WN + nb * 256 + q * 128 + ng * 4;
        int mx, my, mz, mw;
        if (mask_is_int) {
          const int4 mv = *(const int4*)((const int*)mask + moff);
          mx = mv.x; my = mv.y; mz = mv.z; mw = mv.w;
        } else {
          const uchar4 mv = *(const uchar4*)((const unsigned char*)mask + moff);
          mx = mv.x; my = mv.y; mz = mv.z; mw = mv.w;
        }
        if (mx) s[i][nb * 8 + q * 4 + 0] = -1e30f;
        if (my) s[i][nb * 8 + q * 4 + 1] = -1e30f;
        if (mz) s[i][nb * 8 + q * 4 + 2] = -1e30f;
        if (mw) s[i][nb * 8 + q * 4 + 3] = -1e30f;
      }
    float m = -1e30f;
#pragma unroll
    for (int u = 0; u < 64; ++u) m = fmaxf(m, s[i][u]);
#pragma unroll
    for (int off = 16; off > 0; off >>= 1) m = fmaxf(m, __shfl_xor(m, off));
    float sum = 0.0f;
#pragma unroll
    for (int u = 0; u < 64; ++u) {
      const float p = __expf(s[i][u] - m);
      s[i][u] = p;
      sum += p;
    }
#pragma unroll
    for (int off = 16; off > 0; off >>= 1) sum += __shfl_xor(sum, off);
    const float rinv = 1.0f / sum;

    unsigned short* ar = (unsigned short*)(pa + (size_t)(b * E_ + e) * WN / 2);
#pragma unroll
    for (int nb = 0; nb < 8; ++nb)
#pragma unroll
      for (int q = 0; q < 2; ++q) {
        ushort4 pk;
        pk.x = f2bf(s[i][nb * 8 + q * 4 + 0] * rinv);
        pk.y = f2bf(s[i][nb * 8 + q * 4 + 1] * rinv);
        pk.z = f2bf(s[i][nb * 8 + q * 4 + 2] * rinv);
        pk.w = f2bf(s[i][nb * 8 + q * 4 + 3] * rinv);
        *(ushort4*)(ar + nb * 256 + q * 128 + ng * 4) = pk;
      }
  }
}

// ---------------------------------------------------------------------------
// K3: ctx = att @ words. att (bf16) read from d_out rows into LDS, words
// restaged as bf16 stripes; f32 accumulate; overwrite same rows with ctx.
// Thread: eg = t>>5 (e = eg*2+i), wg = t&31 (w = wg*4 + j + 128*q, q<8).
// ---------------------------------------------------------------------------
__global__ __launch_bounds__(256) void k_ctx(const float* __restrict__ words,
                                             float* __restrict__ pa) {
  __shared__ unsigned short att_s[16][2048];  // 64 KB
  __shared__ unsigned short Wb[256][132];     // 67 KB
  const int t = threadIdx.x;
  const int b = blockIdx.x >> 5;
  const int et = blockIdx.x & 31;
  const int e0 = et * 16;
  const int eg = t >> 5;   // 0..7
  const int wg = t & 31;   // 0..31
  const float* wbase = words + (size_t)b * WN * D_;

  // load att rows (bf16 bits) into LDS
  {
    const int row = t >> 4;       // 0..15
    const int cj = t & 15;        // 0..15
    const uint4* pr = (const uint4*)(pa + (size_t)(b * E_ + e0 + row) * D_);
#pragma unroll
    for (int r = 0; r < 16; ++r) {
      const int c = cj + r * 16;            // 0..255 (uint4 index = 8 bf16)
      const uint4 v = pr[c];
      *(uint4*)&att_s[row][c * 8] = v;
    }
  }

  float acc[2][32];
#pragma unroll
  for (int i = 0; i < 2; ++i)
#pragma unroll
    for (int u = 0; u < 32; ++u) acc[i][u] = 0.0f;

  const int nlg = t >> 5;       // 0..7 (load rows)
  const int w4 = (t & 31) * 4;  // 0..124

  for (int nb = 0; nb < 8; ++nb) {
#pragma unroll
    for (int q = 0; q < 8; ++q) {
      __syncthreads();
      // stage words[nb-slice][q-stripe of 128 w] as bf16
#pragma unroll
      for (int r = 0; r < 32; ++r) {
        const int n = nlg + r * 8;
        const float4 v = *(const float4*)(wbase + (size_t)(nb * 256 + n) * D_ + q * 128 + w4);
        ushort4 pk;
        pk.x = f2bf(v.x);
        pk.y = f2bf(v.y);
        pk.z = f2bf(v.z);
        pk.w = f2bf(v.w);
        *(ushort4*)&Wb[n][w4] = pk;
      }
      __syncthreads();
#pragma unroll 4
      for (int n2 = 0; n2 < 128; ++n2) {
        const int n = n2 * 2;
        const ushort4 r0 = *(const ushort4*)&Wb[n][wg * 4];
        const ushort4 r1 = *(const ushort4*)&Wb[n + 1][wg * 4];
        const float w0[4] = {bf2f(r0.x), bf2f(r0.y), bf2f(r0.z), bf2f(r0.w)};
        const float w1[4] = {bf2f(r1.x), bf2f(r1.y), bf2f(r1.z), bf2f(r1.w)};
#pragma unroll
        for (int i = 0; i < 2; ++i) {
          const unsigned int aw = *(const unsigned int*)&att_s[eg * 2 + i][nb * 256 + n];
          const float a0 = bf2f((unsigned short)(aw & 0xffffu));
          const float a1 = bf2f((unsigned short)(aw >> 16));
#pragma unroll
          for (int j = 0; j < 4; ++j)
            acc[i][q * 4 + j] = fmaf(a0, w0[j], fmaf(a1, w1[j], acc[i][q * 4 + j]));
        }
      }
    }
  }

  // store ctx (overwrites att rows; att fully in LDS already)
#pragma unroll
  for (int i = 0; i < 2; ++i) {
    float* orow = pa + (size_t)(b * E_ + e0 + eg * 2 + i) * D_;
#pragma unroll
    for (int q = 0; q < 8; ++q) {
      float4 v;
      v.x = acc[i][q * 4 + 0];
      v.y = acc[i][q * 4 + 1];
      v.z = acc[i][q * 4 + 2];
      v.w = acc[i][q * 4 + 3];
      *(float4*)(orow + q * 128 + wg * 4) = v;
    }
  }
}

extern "C" void kernel_launch(void* const* d_in, const int* in_sizes, int n_in,
                              void* d_out, int out_size, void* d_ws, size_t ws_size,
                              hipStream_t stream) {
  const float* ems = (const float*)d_in[0];
  const float* words = (const float*)d_in[1];
  const void* mask = d_in[2];  // dtype probed on device (uint8 vs int32)
  const float* w_weight = (const float*)d_in[3];
  const float* w_bias = (const float*)d_in[4];
  float* out = (float*)d_out;

  // K0: detect mask element width (writes __device__ g_mask_is_int)
  k_detect<<<1, 64, 0, stream>>>((const unsigned char*)mask);
  // K1: proj -> d_out (scratch)
  k_proj<<<dim3(128, 8), 256, 0, stream>>>(ems, w_weight, w_bias, out);
  // K2: scores + softmax -> att (bf16) into same d_out rows
  k_scores<<<dim3(B_ * (E_ / 16)), 256, 0, stream>>>(words, mask, out);
  // K3: ctx = att @ words -> final output in d_out
  k_ctx<<<dim3(B_ * (E_ / 16)), 256, 0, stream>>>(words, out);
}

// Round 3
// 1188.548 us; speedup vs baseline: 4.3149x; 4.3149x over previous
//
#include <hip/hip_runtime.h>
#include <hip/hip_bf16.h>
#include <stdint.h>

#define B_  32
#define E_  512
#define WN  2048
#define D_  1024

typedef __attribute__((ext_vector_type(8))) short short8;
typedef __attribute__((ext_vector_type(4))) float f32x4;

__device__ int g_mask_is_int;   // 1 if mask buffer is int32 per element, 0 if uint8

__device__ __forceinline__ unsigned short f2bf(float f) {
  unsigned int u = __float_as_uint(f);
  u += 0x7fffu + ((u >> 16) & 1u);   // round-to-nearest-even
  return (unsigned short)(u >> 16);
}
__device__ __forceinline__ float bf2f(unsigned short s) {
  return __uint_as_float(((unsigned int)s) << 16);
}
__device__ __forceinline__ float ftanh(float x) {
  // tanh(x) = 1 - 2/(exp(2x)+1); saturates correctly for |x| large
  float e = __expf(2.0f * x);
  return 1.0f - 2.0f / (e + 1.0f);
}
// XOR-swizzled byte offset within a [128 rows][64 bf16] LDS plane (rows 128B)
__device__ __forceinline__ int swz(int row, int kb) {
  return row * 128 + (kb ^ ((row & 7) << 4));
}
__device__ __forceinline__ uint4 pack8(unsigned short a0, unsigned short a1,
                                       unsigned short a2, unsigned short a3,
                                       unsigned short a4, unsigned short a5,
                                       unsigned short a6, unsigned short a7) {
  uint4 v;
  v.x = (unsigned int)a0 | ((unsigned int)a1 << 16);
  v.y = (unsigned int)a2 | ((unsigned int)a3 << 16);
  v.z = (unsigned int)a4 | ((unsigned int)a5 << 16);
  v.w = (unsigned int)a6 | ((unsigned int)a7 << 16);
  return v;
}

// ---------------------------------------------------------------------------
// K0: detect mask dtype. int32 0/1 data => bytes at offset %4 != 0 are all 0.
// ---------------------------------------------------------------------------
__global__ void k_detect(const unsigned char* __restrict__ m) {
  if (threadIdx.x == 0) {
    int nz = 0;
    for (int i = 0; i < 1024; ++i)
      if ((i & 3) && m[i]) nz++;
    g_mask_is_int = (nz == 0) ? 1 : 0;
  }
}

// ===========================================================================
// FAST PATH (needs ws_size >= 16384*2048*4)
// ===========================================================================

// ---------------------------------------------------------------------------
// k_proj_mfma: proj = tanh(ems @ W^T + bias), split-bf16 3-term MFMA.
// Writes hi/lo bf16 planes. M=16384, N=1024, K=1024. Tile 128x128, BK=64.
// ---------------------------------------------------------------------------
__global__ __launch_bounds__(256, 2) void k_proj_mfma(
    const float* __restrict__ A, const float* __restrict__ W,
    const float* __restrict__ bias,
    unsigned short* __restrict__ outHi, unsigned short* __restrict__ outLo) {
  __shared__ unsigned short lds[32768];  // 64KB: Ahi|Alo|Bhi|Blo planes 16KB each
  char* const ldsb = (char*)lds;
  char* const pAhi = ldsb;
  char* const pAlo = ldsb + 16384;
  char* const pBhi = ldsb + 32768;
  char* const pBlo = ldsb + 49152;
  const int t = threadIdx.x, l = t & 63, wave = t >> 6;
  const int wm = (wave >> 1) * 64, wn = (wave & 1) * 64;
  const int m0 = blockIdx.x * 128, n0 = blockIdx.y * 128;
  const int r = t >> 1, h = t & 1;

  f32x4 acc[4][4];
#pragma unroll
  for (int i = 0; i < 4; ++i)
#pragma unroll
    for (int j = 0; j < 4; ++j) acc[i][j] = (f32x4){0.f, 0.f, 0.f, 0.f};

  f32x4 ar[8], br[8];   // prefetch regs: 32 f32 each operand

  auto load_stage = [&](int s) {
    const float* as = A + (size_t)(m0 + r) * 1024 + s * 64 + h * 32;
    const float* bs = W + (size_t)(n0 + r) * 1024 + s * 64 + h * 32;
#pragma unroll
    for (int i = 0; i < 8; ++i) {
      ar[i] = *(const f32x4*)(as + i * 4);
      br[i] = *(const f32x4*)(bs + i * 4);
    }
  };

  auto write_stage = [&]() {
    unsigned short hA[32], lA[32], hB[32], lB[32];
#pragma unroll
    for (int i = 0; i < 8; ++i)
#pragma unroll
      for (int j = 0; j < 4; ++j) {
        float x = ar[i][j];
        unsigned short hh = f2bf(x);
        hA[i * 4 + j] = hh;
        lA[i * 4 + j] = f2bf(x - bf2f(hh));
        float y = br[i][j];
        unsigned short hb = f2bf(y);
        hB[i * 4 + j] = hb;
        lB[i * 4 + j] = f2bf(y - bf2f(hb));
      }
#pragma unroll
    for (int i = 0; i < 4; ++i) {
      const int kb = h * 64 + i * 16;
      const int o = swz(r, kb);
      *(uint4*)(pAhi + o) = pack8(hA[i*8+0],hA[i*8+1],hA[i*8+2],hA[i*8+3],hA[i*8+4],hA[i*8+5],hA[i*8+6],hA[i*8+7]);
      *(uint4*)(pAlo + o) = pack8(lA[i*8+0],lA[i*8+1],lA[i*8+2],lA[i*8+3],lA[i*8+4],lA[i*8+5],lA[i*8+6],lA[i*8+7]);
      *(uint4*)(pBhi + o) = pack8(hB[i*8+0],hB[i*8+1],hB[i*8+2],hB[i*8+3],hB[i*8+4],hB[i*8+5],hB[i*8+6],hB[i*8+7]);
      *(uint4*)(pBlo + o) = pack8(lB[i*8+0],lB[i*8+1],lB[i*8+2],lB[i*8+3],lB[i*8+4],lB[i*8+5],lB[i*8+6],lB[i*8+7]);
    }
  };

  auto compute_stage = [&]() {
#pragma unroll
    for (int ks = 0; ks < 2; ++ks) {
      short8 ah[4], al[4], bh[4], bl[4];
      const int kb = ks * 64 + (l >> 4) * 16;
#pragma unroll
      for (int f = 0; f < 4; ++f) {
        const int oa = swz(wm + f * 16 + (l & 15), kb);
        ah[f] = *(const short8*)(pAhi + oa);
        al[f] = *(const short8*)(pAlo + oa);
        const int ob = swz(wn + f * 16 + (l & 15), kb);
        bh[f] = *(const short8*)(pBhi + ob);
        bl[f] = *(const short8*)(pBlo + ob);
      }
#pragma unroll
      for (int fm = 0; fm < 4; ++fm)
#pragma unroll
        for (int fn = 0; fn < 4; ++fn) {
          acc[fm][fn] = __builtin_amdgcn_mfma_f32_16x16x32_bf16(ah[fm], bh[fn], acc[fm][fn], 0, 0, 0);
          acc[fm][fn] = __builtin_amdgcn_mfma_f32_16x16x32_bf16(al[fm], bh[fn], acc[fm][fn], 0, 0, 0);
          acc[fm][fn] = __builtin_amdgcn_mfma_f32_16x16x32_bf16(ah[fm], bl[fn], acc[fm][fn], 0, 0, 0);
        }
    }
  };

  load_stage(0);
  write_stage();
  __syncthreads();
  for (int s = 0; s < 15; ++s) {
    load_stage(s + 1);
    compute_stage();
    __syncthreads();
    write_stage();
    __syncthreads();
  }
  compute_stage();

  // epilogue: tanh(x + bias), split to hi/lo, LDS-transpose for coalesced stores
  float bcol[4];
#pragma unroll
  for (int fn = 0; fn < 4; ++fn) bcol[fn] = bias[n0 + wn + fn * 16 + (l & 15)];
#pragma unroll
  for (int fm = 0; fm < 4; ++fm)
#pragma unroll
    for (int fn = 0; fn < 4; ++fn)
#pragma unroll
      for (int q = 0; q < 4; ++q)
        acc[fm][fn][q] = ftanh(acc[fm][fn][q] + bcol[fn]);

  unsigned short* ldsT = lds;  // reused as [128][136]
  const int rr = t >> 1, ch = (t & 1) * 64;
  // pass 1: hi plane
  __syncthreads();
#pragma unroll
  for (int fm = 0; fm < 4; ++fm)
#pragma unroll
    for (int fn = 0; fn < 4; ++fn)
#pragma unroll
      for (int q = 0; q < 4; ++q) {
        const int rl = wm + fm * 16 + (l >> 4) * 4 + q;
        const int cl = wn + fn * 16 + (l & 15);
        ldsT[rl * 136 + cl] = f2bf(acc[fm][fn][q]);
      }
  __syncthreads();
#pragma unroll
  for (int i = 0; i < 8; ++i) {
    uint4 v = *(const uint4*)(ldsT + rr * 136 + ch + i * 8);
    *(uint4*)(outHi + (size_t)(m0 + rr) * 1024 + n0 + ch + i * 8) = v;
  }
  // pass 2: lo plane
  __syncthreads();
#pragma unroll
  for (int fm = 0; fm < 4; ++fm)
#pragma unroll
    for (int fn = 0; fn < 4; ++fn)
#pragma unroll
      for (int q = 0; q < 4; ++q) {
        const int rl = wm + fm * 16 + (l >> 4) * 4 + q;
        const int cl = wn + fn * 16 + (l & 15);
        const float x = acc[fm][fn][q];
        const unsigned short hh = f2bf(x);
        ldsT[rl * 136 + cl] = f2bf(x - bf2f(hh));
      }
  __syncthreads();
#pragma unroll
  for (int i = 0; i < 8; ++i) {
    uint4 v = *(const uint4*)(ldsT + rr * 136 + ch + i * 8);
    *(uint4*)(outLo + (size_t)(m0 + rr) * 1024 + n0 + ch + i * 8) = v;
  }
}

// ---------------------------------------------------------------------------
// k_scores_mfma: scores = proj @ words^T (split-bf16 3-term), f32 -> ws.
// Per b: M=512, N=2048, K=1024. grid(4,16,32). Tile 128x128, BK=64.
// ---------------------------------------------------------------------------
__global__ __launch_bounds__(256, 2) void k_scores_mfma(
    const unsigned short* __restrict__ pHi, const unsigned short* __restrict__ pLo,
    const float* __restrict__ words, float* __restrict__ sc) {
  __shared__ unsigned short lds[32768];
  char* const ldsb = (char*)lds;
  char* const pAhi = ldsb;
  char* const pAlo = ldsb + 16384;
  char* const pBhi = ldsb + 32768;
  char* const pBlo = ldsb + 49152;
  const int t = threadIdx.x, l = t & 63, wave = t >> 6;
  const int wm = (wave >> 1) * 64, wn = (wave & 1) * 64;
  const int b = blockIdx.z;
  const int m0 = blockIdx.x * 128, n0 = blockIdx.y * 128;
  const int mg = b * 512 + m0;
  const float* wB = words + (size_t)b * WN * D_;
  const int r = t >> 1, h = t & 1;

  f32x4 acc[4][4];
#pragma unroll
  for (int i = 0; i < 4; ++i)
#pragma unroll
    for (int j = 0; j < 4; ++j) acc[i][j] = (f32x4){0.f, 0.f, 0.f, 0.f};

  uint4 avh[4], avl[4];   // A planes are already bf16: raw 16B moves
  f32x4 br[8];

  auto load_stage = [&](int s) {
    const unsigned short* ah_ = pHi + (size_t)(mg + r) * 1024 + s * 64 + h * 32;
    const unsigned short* al_ = pLo + (size_t)(mg + r) * 1024 + s * 64 + h * 32;
#pragma unroll
    for (int i = 0; i < 4; ++i) {
      avh[i] = ((const uint4*)ah_)[i];
      avl[i] = ((const uint4*)al_)[i];
    }
    const float* bs = wB + (size_t)(n0 + r) * 1024 + s * 64 + h * 32;
#pragma unroll
    for (int i = 0; i < 8; ++i) br[i] = *(const f32x4*)(bs + i * 4);
  };

  auto write_stage = [&]() {
#pragma unroll
    for (int i = 0; i < 4; ++i) {
      const int o = swz(r, h * 64 + i * 16);
      *(uint4*)(pAhi + o) = avh[i];
      *(uint4*)(pAlo + o) = avl[i];
    }
    unsigned short hB[32], lB[32];
#pragma unroll
    for (int i = 0; i < 8; ++i)
#pragma unroll
      for (int j = 0; j < 4; ++j) {
        float y = br[i][j];
        unsigned short hb = f2bf(y);
        hB[i * 4 + j] = hb;
        lB[i * 4 + j] = f2bf(y - bf2f(hb));
      }
#pragma unroll
    for (int i = 0; i < 4; ++i) {
      const int o = swz(r, h * 64 + i * 16);
      *(uint4*)(pBhi + o) = pack8(hB[i*8+0],hB[i*8+1],hB[i*8+2],hB[i*8+3],hB[i*8+4],hB[i*8+5],hB[i*8+6],hB[i*8+7]);
      *(uint4*)(pBlo + o) = pack8(lB[i*8+0],lB[i*8+1],lB[i*8+2],lB[i*8+3],lB[i*8+4],lB[i*8+5],lB[i*8+6],lB[i*8+7]);
    }
  };

  auto compute_stage = [&]() {
#pragma unroll
    for (int ks = 0; ks < 2; ++ks) {
      short8 ah[4], al[4], bh[4], bl[4];
      const int kb = ks * 64 + (l >> 4) * 16;
#pragma unroll
      for (int f = 0; f < 4; ++f) {
        const int oa = swz(wm + f * 16 + (l & 15), kb);
        ah[f] = *(const short8*)(pAhi + oa);
        al[f] = *(const short8*)(pAlo + oa);
        const int ob = swz(wn + f * 16 + (l & 15), kb);
        bh[f] = *(const short8*)(pBhi + ob);
        bl[f] = *(const short8*)(pBlo + ob);
      }
#pragma unroll
      for (int fm = 0; fm < 4; ++fm)
#pragma unroll
        for (int fn = 0; fn < 4; ++fn) {
          acc[fm][fn] = __builtin_amdgcn_mfma_f32_16x16x32_bf16(ah[fm], bh[fn], acc[fm][fn], 0, 0, 0);
          acc[fm][fn] = __builtin_amdgcn_mfma_f32_16x16x32_bf16(al[fm], bh[fn], acc[fm][fn], 0, 0, 0);
          acc[fm][fn] = __builtin_amdgcn_mfma_f32_16x16x32_bf16(ah[fm], bl[fn], acc[fm][fn], 0, 0, 0);
        }
    }
  };

  load_stage(0);
  write_stage();
  __syncthreads();
  for (int s = 0; s < 15; ++s) {
    load_stage(s + 1);
    compute_stage();
    __syncthreads();
    write_stage();
    __syncthreads();
  }
  compute_stage();

  // store f32 scores
#pragma unroll
  for (int fm = 0; fm < 4; ++fm)
#pragma unroll
    for (int fn = 0; fn < 4; ++fn)
#pragma unroll
      for (int q = 0; q < 4; ++q) {
        const int rl = wm + fm * 16 + (l >> 4) * 4 + q;
        const int cl = wn + fn * 16 + (l & 15);
        sc[((size_t)b * 512 + m0 + rl) * 2048 + n0 + cl] = acc[fm][fn][q];
      }
}

// ---------------------------------------------------------------------------
// k_softmax: per row (16384): read 2048 f32 scores from ws, mask, exact
// softmax, write 2048 bf16 att in-place at the row base.
// ---------------------------------------------------------------------------
__global__ __launch_bounds__(256) void k_softmax(float* __restrict__ ws,
                                                 const void* __restrict__ mask) {
  __shared__ float red[8];
  const int row = blockIdx.x;
  const int t = threadIdx.x;
  const int wave = t >> 6;
  float* rp = ws + (size_t)row * 2048;
  float v[8];
  {
    f32x4 v0 = *(const f32x4*)(rp + t * 8);
    f32x4 v1 = *(const f32x4*)(rp + t * 8 + 4);
#pragma unroll
    for (int i = 0; i < 4; ++i) { v[i] = v0[i]; v[4 + i] = v1[i]; }
  }
  if (g_mask_is_int) {
    const int* mp = (const int*)mask + (size_t)row * 2048 + t * 8;
    const int4 m0 = *(const int4*)mp;
    const int4 m1 = *(const int4*)(mp + 4);
    if (m0.x) v[0] = -INFINITY;
    if (m0.y) v[1] = -INFINITY;
    if (m0.z) v[2] = -INFINITY;
    if (m0.w) v[3] = -INFINITY;
    if (m1.x) v[4] = -INFINITY;
    if (m1.y) v[5] = -INFINITY;
    if (m1.z) v[6] = -INFINITY;
    if (m1.w) v[7] = -INFINITY;
  } else {
    const unsigned char* mp = (const unsigned char*)mask + (size_t)row * 2048 + t * 8;
    const uchar4 m0 = *(const uchar4*)mp;
    const uchar4 m1 = *(const uchar4*)(mp + 4);
    if (m0.x) v[0] = -INFINITY;
    if (m0.y) v[1] = -INFINITY;
    if (m0.z) v[2] = -INFINITY;
    if (m0.w) v[3] = -INFINITY;
    if (m1.x) v[4] = -INFINITY;
    if (m1.y) v[5] = -INFINITY;
    if (m1.z) v[6] = -INFINITY;
    if (m1.w) v[7] = -INFINITY;
  }
  float mx = v[0];
#pragma unroll
  for (int i = 1; i < 8; ++i) mx = fmaxf(mx, v[i]);
#pragma unroll
  for (int off = 32; off > 0; off >>= 1) mx = fmaxf(mx, __shfl_xor(mx, off));
  if ((t & 63) == 0) red[wave] = mx;
  __syncthreads();
  mx = fmaxf(fmaxf(red[0], red[1]), fmaxf(red[2], red[3]));
  float e[8];
  float sum = 0.0f;
#pragma unroll
  for (int i = 0; i < 8; ++i) {
    e[i] = __expf(v[i] - mx);
    sum += e[i];
  }
#pragma unroll
  for (int off = 32; off > 0; off >>= 1) sum += __shfl_xor(sum, off);
  if ((t & 63) == 0) red[4 + wave] = sum;
  __syncthreads();
  const float tot = (red[4] + red[5]) + (red[6] + red[7]);
  const float rinv = 1.0f / tot;
  unsigned short* op = (unsigned short*)rp;
  ushort4 o0, o1;
  o0.x = f2bf(e[0] * rinv); o0.y = f2bf(e[1] * rinv);
  o0.z = f2bf(e[2] * rinv); o0.w = f2bf(e[3] * rinv);
  o1.x = f2bf(e[4] * rinv); o1.y = f2bf(e[5] * rinv);
  o1.z = f2bf(e[6] * rinv); o1.w = f2bf(e[7] * rinv);
  *(ushort4*)(op + t * 8) = o0;
  *(ushort4*)(op + t * 8 + 4) = o1;
}

// ---------------------------------------------------------------------------
// k_pv: ctx = att @ words (bf16 MFMA). Per b: M=512, N=1024, K=2048.
// grid(4,8,32). Tile 128x128, BK=64. att rows stride 4096 ushorts (in ws).
// B staged transposed (words[n][w] -> LDS [w][n]) with bf16 convert.
// ---------------------------------------------------------------------------
__global__ __launch_bounds__(256, 2) void k_pv(
    const unsigned short* __restrict__ att, const float* __restrict__ words,
    float* __restrict__ out) {
  __shared__ unsigned short lds[16384];  // 32KB: A 16KB | Bt 16KB
  char* const ldsb = (char*)lds;
  char* const pA = ldsb;
  char* const pB = ldsb + 16384;
  const int t = threadIdx.x, l = t & 63, wave = t >> 6;
  const int wm = (wave >> 1) * 64, wn = (wave & 1) * 64;
  const int b = blockIdx.z;
  const int m0 = blockIdx.x * 128, w0 = blockIdx.y * 128;
  const unsigned short* attB = att + (size_t)b * 512 * 4096;
  const float* wB = words + (size_t)b * WN * D_;
  const int r = t >> 1, h = t & 1;
  const int w4 = (t & 31) * 4, np = t >> 5;

  f32x4 acc[4][4];
#pragma unroll
  for (int i = 0; i < 4; ++i)
#pragma unroll
    for (int j = 0; j < 4; ++j) acc[i][j] = (f32x4){0.f, 0.f, 0.f, 0.f};

  uint4 av[4];
  f32x4 bva[4], bvb[4];

  auto load_stage = [&](int s) {
    const unsigned short* as = attB + (size_t)(m0 + r) * 4096 + s * 64 + h * 32;
#pragma unroll
    for (int i = 0; i < 4; ++i) av[i] = ((const uint4*)as)[i];
#pragma unroll
    for (int j = 0; j < 4; ++j) {
      const int n = (np + j * 8) * 2;
      bva[j] = *(const f32x4*)(wB + (size_t)(s * 64 + n) * 1024 + w0 + w4);
      bvb[j] = *(const f32x4*)(wB + (size_t)(s * 64 + n + 1) * 1024 + w0 + w4);
    }
  };

  auto write_stage = [&]() {
#pragma unroll
    for (int i = 0; i < 4; ++i)
      *(uint4*)(pA + swz(r, h * 64 + i * 16)) = av[i];
#pragma unroll
    for (int j = 0; j < 4; ++j) {
      const int n2 = np + j * 8;
#pragma unroll
      for (int i = 0; i < 4; ++i) {
        const int w = w4 + i;
        const unsigned int pk =
            (unsigned int)f2bf(bva[j][i]) | ((unsigned int)f2bf(bvb[j][i]) << 16);
        *(unsigned int*)(pB + (w * 128 + ((n2 * 4) ^ ((w & 7) << 4)))) = pk;
      }
    }
  };

  auto compute_stage = [&]() {
#pragma unroll
    for (int ks = 0; ks < 2; ++ks) {
      short8 a[4], bf[4];
      const int kb = ks * 64 + (l >> 4) * 16;
#pragma unroll
      for (int f = 0; f < 4; ++f) {
        a[f] = *(const short8*)(pA + swz(wm + f * 16 + (l & 15), kb));
        bf[f] = *(const short8*)(pB + swz(wn + f * 16 + (l & 15), kb));
      }
#pragma unroll
      for (int fm = 0; fm < 4; ++fm)
#pragma unroll
        for (int fn = 0; fn < 4; ++fn)
          acc[fm][fn] = __builtin_amdgcn_mfma_f32_16x16x32_bf16(a[fm], bf[fn], acc[fm][fn], 0, 0, 0);
    }
  };

  load_stage(0);
  write_stage();
  __syncthreads();
  for (int s = 0; s < 31; ++s) {
    load_stage(s + 1);
    compute_stage();
    __syncthreads();
    write_stage();
    __syncthreads();
  }
  compute_stage();

#pragma unroll
  for (int fm = 0; fm < 4; ++fm)
#pragma unroll
    for (int fn = 0; fn < 4; ++fn)
#pragma unroll
      for (int q = 0; q < 4; ++q) {
        const int rl = wm + fm * 16 + (l >> 4) * 4 + q;
        const int cl = wn + fn * 16 + (l & 15);
        out[((size_t)b * 512 + m0 + rl) * 1024 + w0 + cl] = acc[fm][fn][q];
      }
}

// ===========================================================================
// FALLBACK PATH (round-2 verified kernels; used if ws too small)
// ===========================================================================
__global__ __launch_bounds__(256, 4) void k_proj(const float* __restrict__ A,
                                                 const float* __restrict__ W,
                                                 const float* __restrict__ bias,
                                                 float* __restrict__ out) {
  __shared__ float As[32][132];
  __shared__ float Bs[32][132];
  const int t = threadIdx.x;
  const int m0 = blockIdx.x * 128;
  const int n0 = blockIdx.y * 128;
  const int tm = t >> 4;
  const int tn = t & 15;
  const int lrow = t >> 1;
  const int lk = (t & 1) * 16;

  float acc[8][8];
#pragma unroll
  for (int i = 0; i < 8; ++i)
#pragma unroll
    for (int j = 0; j < 8; ++j) acc[i][j] = 0.0f;

  const float* Arow = A + (size_t)(m0 + lrow) * D_ + lk;
  const float* Wrow = W + (size_t)(n0 + lrow) * D_ + lk;

  for (int k0 = 0; k0 < D_; k0 += 32) {
    __syncthreads();
#pragma unroll
    for (int j = 0; j < 4; ++j) {
      const float4 va = *(const float4*)(Arow + k0 + j * 4);
      As[lk + j * 4 + 0][lrow] = va.x;
      As[lk + j * 4 + 1][lrow] = va.y;
      As[lk + j * 4 + 2][lrow] = va.z;
      As[lk + j * 4 + 3][lrow] = va.w;
      const float4 vb = *(const float4*)(Wrow + k0 + j * 4);
      Bs[lk + j * 4 + 0][lrow] = vb.x;
      Bs[lk + j * 4 + 1][lrow] = vb.y;
      Bs[lk + j * 4 + 2][lrow] = vb.z;
      Bs[lk + j * 4 + 3][lrow] = vb.w;
    }
    __syncthreads();
#pragma unroll 8
    for (int k = 0; k < 32; ++k) {
      float a[8], bb[8];
      *(float4*)(a + 0) = *(const float4*)&As[k][tm * 4];
      *(float4*)(a + 4) = *(const float4*)&As[k][tm * 4 + 64];
      *(float4*)(bb + 0) = *(const float4*)&Bs[k][tn * 4];
      *(float4*)(bb + 4) = *(const float4*)&Bs[k][tn * 4 + 64];
#pragma unroll
      for (int i = 0; i < 8; ++i)
#pragma unroll
        for (int j = 0; j < 8; ++j) acc[i][j] = fmaf(a[i], bb[j], acc[i][j]);
    }
  }

  float bn[8];
#pragma unroll
  for (int j = 0; j < 8; ++j) bn[j] = bias[n0 + tn * 4 + (j & 3) + (j >> 2) * 64];
#pragma unroll
  for (int i = 0; i < 8; ++i) {
    const int m = m0 + tm * 4 + (i & 3) + (i >> 2) * 64;
    float4 v0, v1;
    v0.x = tanhf(acc[i][0] + bn[0]);
    v0.y = tanhf(acc[i][1] + bn[1]);
    v0.z = tanhf(acc[i][2] + bn[2]);
    v0.w = tanhf(acc[i][3] + bn[3]);
    v1.x = tanhf(acc[i][4] + bn[4]);
    v1.y = tanhf(acc[i][5] + bn[5]);
    v1.z = tanhf(acc[i][6] + bn[6]);
    v1.w = tanhf(acc[i][7] + bn[7]);
    *(float4*)(out + (size_t)m * D_ + n0 + tn * 4) = v0;
    *(float4*)(out + (size_t)m * D_ + n0 + tn * 4 + 64) = v1;
  }
}

__global__ __launch_bounds__(256) void k_scores(const float* __restrict__ words,
                                                const void* __restrict__ mask,
                                                float* __restrict__ pa) {
  __shared__ float Pt[1024][18];
  __shared__ float Ws[64][268];
  const int t = threadIdx.x;
  const int b = blockIdx.x >> 5;
  const int et = blockIdx.x & 31;
  const int e0 = et * 16;
  const int eg = t >> 5;
  const int ng = t & 31;
  const int mask_is_int = g_mask_is_int;
  const float* wbase = words + (size_t)b * WN * D_;

  {
    const int row = t >> 4;
    const int dj = (t & 15) * 4;
    const float* pr = pa + (size_t)(b * E_ + e0 + row) * D_;
#pragma unroll
    for (int rr = 0; rr < 16; ++rr) {
      const float4 v = *(const float4*)(pr + dj + rr * 64);
      Pt[dj + rr * 64 + 0][row] = v.x;
      Pt[dj + rr * 64 + 1][row] = v.y;
      Pt[dj + rr * 64 + 2][row] = v.z;
      Pt[dj + rr * 64 + 3][row] = v.w;
    }
  }

  float s[2][64];
#pragma unroll
  for (int i = 0; i < 2; ++i)
#pragma unroll
    for (int u = 0; u < 64; ++u) s[i][u] = 0.0f;

  const int nl = t >> 3;
  const int d4 = (t & 7) * 4;

  for (int dk = 0; dk < D_; dk += 64) {
#pragma unroll
    for (int nb = 0; nb < 8; ++nb) {
      __syncthreads();
#pragma unroll
      for (int rr = 0; rr < 8; ++rr) {
#pragma unroll
        for (int hh = 0; hh < 2; ++hh) {
          const int n = nl + rr * 32;
          const int d = d4 + hh * 32;
          const float4 v = *(const float4*)(wbase + (size_t)(nb * 256 + n) * D_ + dk + d);
          Ws[d + 0][n] = v.x;
          Ws[d + 1][n] = v.y;
          Ws[d + 2][n] = v.z;
          Ws[d + 3][n] = v.w;
        }
      }
      __syncthreads();
#pragma unroll 2
      for (int k = 0; k < 64; ++k) {
        const float2 a = *(const float2*)&Pt[dk + k][eg * 2];
        const float4 b0 = *(const float4*)&Ws[k][ng * 4];
        const float4 b1 = *(const float4*)&Ws[k][128 + ng * 4];
        const float aa[2] = {a.x, a.y};
        const float bb[8] = {b0.x, b0.y, b0.z, b0.w, b1.x, b1.y, b1.z, b1.w};
#pragma unroll
        for (int i = 0; i < 2; ++i)
#pragma unroll
          for (int u = 0; u < 8; ++u)
            s[i][nb * 8 + u] = fmaf(aa[i], bb[u], s[i][nb * 8 + u]);
      }
    }
  }

#pragma unroll
  for (int i = 0; i < 2; ++i) {
    const int e = e0 + eg * 2 + i;
#pragma unroll
    for (int nb = 0; nb < 8; ++nb)
#pragma unroll
      for (int q = 0; q < 2; ++q) {
        const size_t moff = (size_t)(b * E_ + e) * WN + nb * 256 + q * 128 + ng * 4;
        int mx, my, mz, mw;
        if (mask_is_int) {
          const int4 mv = *(const int4*)((const int*)mask + moff);
          mx = mv.x; my = mv.y; mz = mv.z; mw = mv.w;
        } else {
          const uchar4 mv = *(const uchar4*)((const unsigned char*)mask + moff);
          mx = mv.x; my = mv.y; mz = mv.z; mw = mv.w;
        }
        if (mx) s[i][nb * 8 + q * 4 + 0] = -1e30f;
        if (my) s[i][nb * 8 + q * 4 + 1] = -1e30f;
        if (mz) s[i][nb * 8 + q * 4 + 2] = -1e30f;
        if (mw) s[i][nb * 8 + q * 4 + 3] = -1e30f;
      }
    float m = -1e30f;
#pragma unroll
    for (int u = 0; u < 64; ++u) m = fmaxf(m, s[i][u]);
#pragma unroll
    for (int off = 16; off > 0; off >>= 1) m = fmaxf(m, __shfl_xor(m, off));
    float sum = 0.0f;
#pragma unroll
    for (int u = 0; u < 64; ++u) {
      const float p = __expf(s[i][u] - m);
      s[i][u] = p;
      sum += p;
    }
#pragma unroll
    for (int off = 16; off > 0; off >>= 1) sum += __shfl_xor(sum, off);
    const float rinv = 1.0f / sum;

    unsigned short* ar2 = (unsigned short*)(pa + (size_t)(b * E_ + e) * WN / 2);
#pragma unroll
    for (int nb = 0; nb < 8; ++nb)
#pragma unroll
      for (int q = 0; q < 2; ++q) {
        ushort4 pk;
        pk.x = f2bf(s[i][nb * 8 + q * 4 + 0] * rinv);
        pk.y = f2bf(s[i][nb * 8 + q * 4 + 1] * rinv);
        pk.z = f2bf(s[i][nb * 8 + q * 4 + 2] * rinv);
        pk.w = f2bf(s[i][nb * 8 + q * 4 + 3] * rinv);
        *(ushort4*)(ar2 + nb * 256 + q * 128 + ng * 4) = pk;
      }
  }
}

__global__ __launch_bounds__(256) void k_ctx(const float* __restrict__ words,
                                             float* __restrict__ pa) {
  __shared__ unsigned short att_s[16][2048];
  __shared__ unsigned short Wb[256][132];
  const int t = threadIdx.x;
  const int b = blockIdx.x >> 5;
  const int et = blockIdx.x & 31;
  const int e0 = et * 16;
  const int eg = t >> 5;
  const int wg = t & 31;
  const float* wbase = words + (size_t)b * WN * D_;

  {
    const int row = t >> 4;
    const int cj = t & 15;
    const uint4* pr = (const uint4*)(pa + (size_t)(b * E_ + e0 + row) * D_);
#pragma unroll
    for (int rr = 0; rr < 16; ++rr) {
      const int c = cj + rr * 16;
      const uint4 v = pr[c];
      *(uint4*)&att_s[row][c * 8] = v;
    }
  }

  float acc[2][32];
#pragma unroll
  for (int i = 0; i < 2; ++i)
#pragma unroll
    for (int u = 0; u < 32; ++u) acc[i][u] = 0.0f;

  const int nlg = t >> 5;
  const int w4 = (t & 31) * 4;

  for (int nb = 0; nb < 8; ++nb) {
#pragma unroll
    for (int q = 0; q < 8; ++q) {
      __syncthreads();
#pragma unroll
      for (int rr = 0; rr < 32; ++rr) {
        const int n = nlg + rr * 8;
        const float4 v = *(const float4*)(wbase + (size_t)(nb * 256 + n) * D_ + q * 128 + w4);
        ushort4 pk;
        pk.x = f2bf(v.x);
        pk.y = f2bf(v.y);
        pk.z = f2bf(v.z);
        pk.w = f2bf(v.w);
        *(ushort4*)&Wb[n][w4] = pk;
      }
      __syncthreads();
#pragma unroll 4
      for (int n2 = 0; n2 < 128; ++n2) {
        const int n = n2 * 2;
        const ushort4 r0 = *(const ushort4*)&Wb[n][wg * 4];
        const ushort4 r1 = *(const ushort4*)&Wb[n + 1][wg * 4];
        const float w0[4] = {bf2f(r0.x), bf2f(r0.y), bf2f(r0.z), bf2f(r0.w)};
        const float w1[4] = {bf2f(r1.x), bf2f(r1.y), bf2f(r1.z), bf2f(r1.w)};
#pragma unroll
        for (int i = 0; i < 2; ++i) {
          const unsigned int aw = *(const unsigned int*)&att_s[eg * 2 + i][nb * 256 + n];
          const float a0 = bf2f((unsigned short)(aw & 0xffffu));
          const float a1 = bf2f((unsigned short)(aw >> 16));
#pragma unroll
          for (int j = 0; j < 4; ++j)
            acc[i][q * 4 + j] = fmaf(a0, w0[j], fmaf(a1, w1[j], acc[i][q * 4 + j]));
        }
      }
    }
  }

#pragma unroll
  for (int i = 0; i < 2; ++i) {
    float* orow = pa + (size_t)(b * E_ + e0 + eg * 2 + i) * D_;
#pragma unroll
    for (int q = 0; q < 8; ++q) {
      float4 v;
      v.x = acc[i][q * 4 + 0];
      v.y = acc[i][q * 4 + 1];
      v.z = acc[i][q * 4 + 2];
      v.w = acc[i][q * 4 + 3];
      *(float4*)(orow + q * 128 + wg * 4) = v;
    }
  }
}

extern "C" void kernel_launch(void* const* d_in, const int* in_sizes, int n_in,
                              void* d_out, int out_size, void* d_ws, size_t ws_size,
                              hipStream_t stream) {
  const float* ems = (const float*)d_in[0];
  const float* words = (const float*)d_in[1];
  const void* mask = d_in[2];
  const float* w_weight = (const float*)d_in[3];
  const float* w_bias = (const float*)d_in[4];

  k_detect<<<1, 64, 0, stream>>>((const unsigned char*)mask);

  const size_t ws_need = (size_t)16384 * 2048 * 4;  // f32 scores, att in-place
  if (ws_size >= ws_need) {
    unsigned short* hiP = (unsigned short*)d_out;
    unsigned short* loP = hiP + (size_t)16384 * 1024;
    float* ws = (float*)d_ws;
    k_proj_mfma<<<dim3(128, 8), 256, 0, stream>>>(ems, w_weight, w_bias, hiP, loP);
    k_scores_mfma<<<dim3(4, 16, 32), 256, 0, stream>>>(hiP, loP, words, ws);
    k_softmax<<<dim3(16384), 256, 0, stream>>>(ws, mask);
    k_pv<<<dim3(4, 8, 32), 256, 0, stream>>>((const unsigned short*)d_ws, words,
                                             (float*)d_out);
  } else {
    float* out = (float*)d_out;
    k_proj<<<dim3(128, 8), 256, 0, stream>>>(ems, w_weight, w_bias, out);
    k_scores<<<dim3(B_ * (E_ / 16)), 256, 0, stream>>>(words, mask, out);
    k_ctx<<<dim3(B_ * (E_ / 16)), 256, 0, stream>>>(words, out);
  }
}

// Round 5
// 907.272 us; speedup vs baseline: 5.6526x; 1.3100x over previous
//
#include <hip/hip_runtime.h>
#include <hip/hip_bf16.h>
#include <stdint.h>

#define B_  32
#define E_  512
#define WN  2048
#define D_  1024

typedef __attribute__((ext_vector_type(8))) short short8;
typedef __attribute__((ext_vector_type(4))) float f32x4;

__device__ int g_mask_is_int;   // 1 if mask buffer is int32 per element, 0 if uint8

__device__ __forceinline__ unsigned short f2bf(float f) {
  unsigned int u = __float_as_uint(f);
  u += 0x7fffu + ((u >> 16) & 1u);   // round-to-nearest-even
  return (unsigned short)(u >> 16);
}
__device__ __forceinline__ float bf2f(unsigned short s) {
  return __uint_as_float(((unsigned int)s) << 16);
}
__device__ __forceinline__ float ftanh(float x) {
  float e = __expf(2.0f * x);
  return 1.0f - 2.0f / (e + 1.0f);
}
// XOR-swizzled byte offset within a [rows][128B] LDS plane
__device__ __forceinline__ int swz(int row, int kb) {
  return row * 128 + (kb ^ ((row & 7) << 4));
}
__device__ __forceinline__ uint4 pack8(unsigned short a0, unsigned short a1,
                                       unsigned short a2, unsigned short a3,
                                       unsigned short a4, unsigned short a5,
                                       unsigned short a6, unsigned short a7) {
  uint4 v;
  v.x = (unsigned int)a0 | ((unsigned int)a1 << 16);
  v.y = (unsigned int)a2 | ((unsigned int)a3 << 16);
  v.z = (unsigned int)a4 | ((unsigned int)a5 << 16);
  v.w = (unsigned int)a6 | ((unsigned int)a7 << 16);
  return v;
}

// ---------------------------------------------------------------------------
// K0: detect mask dtype. int32 0/1 data => bytes at offset %4 != 0 are all 0.
// ---------------------------------------------------------------------------
__global__ void k_detect(const unsigned char* __restrict__ m) {
  if (threadIdx.x == 0) {
    int nz = 0;
    for (int i = 0; i < 1024; ++i)
      if ((i & 3) && m[i]) nz++;
    g_mask_is_int = (nz == 0) ? 1 : 0;
  }
}

// ===========================================================================
// FAST PATH
// ===========================================================================

// ---------------------------------------------------------------------------
// k_proj_mfma: proj = tanh(ems @ W^T + bias), split-bf16 3-term MFMA.
// ---------------------------------------------------------------------------
__global__ __launch_bounds__(256, 2) void k_proj_mfma(
    const float* __restrict__ A, const float* __restrict__ W,
    const float* __restrict__ bias,
    unsigned short* __restrict__ outHi, unsigned short* __restrict__ outLo) {
  __shared__ unsigned short lds[32768];  // 64KB: Ahi|Alo|Bhi|Blo planes 16KB each
  char* const ldsb = (char*)lds;
  char* const pAhi = ldsb;
  char* const pAlo = ldsb + 16384;
  char* const pBhi = ldsb + 32768;
  char* const pBlo = ldsb + 49152;
  const int t = threadIdx.x, l = t & 63, wave = t >> 6;
  const int wm = (wave >> 1) * 64, wn = (wave & 1) * 64;
  const int m0 = blockIdx.x * 128, n0 = blockIdx.y * 128;
  const int r = t >> 1, h = t & 1;

  f32x4 acc[4][4];
#pragma unroll
  for (int i = 0; i < 4; ++i)
#pragma unroll
    for (int j = 0; j < 4; ++j) acc[i][j] = (f32x4){0.f, 0.f, 0.f, 0.f};

  f32x4 ar[8], br[8];

  auto load_stage = [&](int s) {
    const float* as = A + (size_t)(m0 + r) * 1024 + s * 64 + h * 32;
    const float* bs = W + (size_t)(n0 + r) * 1024 + s * 64 + h * 32;
#pragma unroll
    for (int i = 0; i < 8; ++i) {
      ar[i] = *(const f32x4*)(as + i * 4);
      br[i] = *(const f32x4*)(bs + i * 4);
    }
  };

  auto write_stage = [&]() {
    unsigned short hA[32], lA[32], hB[32], lB[32];
#pragma unroll
    for (int i = 0; i < 8; ++i)
#pragma unroll
      for (int j = 0; j < 4; ++j) {
        float x = ar[i][j];
        unsigned short hh = f2bf(x);
        hA[i * 4 + j] = hh;
        lA[i * 4 + j] = f2bf(x - bf2f(hh));
        float y = br[i][j];
        unsigned short hb = f2bf(y);
        hB[i * 4 + j] = hb;
        lB[i * 4 + j] = f2bf(y - bf2f(hb));
      }
#pragma unroll
    for (int i = 0; i < 4; ++i) {
      const int kb = h * 64 + i * 16;
      const int o = swz(r, kb);
      *(uint4*)(pAhi + o) = pack8(hA[i*8+0],hA[i*8+1],hA[i*8+2],hA[i*8+3],hA[i*8+4],hA[i*8+5],hA[i*8+6],hA[i*8+7]);
      *(uint4*)(pAlo + o) = pack8(lA[i*8+0],lA[i*8+1],lA[i*8+2],lA[i*8+3],lA[i*8+4],lA[i*8+5],lA[i*8+6],lA[i*8+7]);
      *(uint4*)(pBhi + o) = pack8(hB[i*8+0],hB[i*8+1],hB[i*8+2],hB[i*8+3],hB[i*8+4],hB[i*8+5],hB[i*8+6],hB[i*8+7]);
      *(uint4*)(pBlo + o) = pack8(lB[i*8+0],lB[i*8+1],lB[i*8+2],lB[i*8+3],lB[i*8+4],lB[i*8+5],lB[i*8+6],lB[i*8+7]);
    }
  };

  auto compute_stage = [&]() {
#pragma unroll
    for (int ks = 0; ks < 2; ++ks) {
      short8 ah[4], al[4], bh[4], bl[4];
      const int kb = ks * 64 + (l >> 4) * 16;
#pragma unroll
      for (int f = 0; f < 4; ++f) {
        const int oa = swz(wm + f * 16 + (l & 15), kb);
        ah[f] = *(const short8*)(pAhi + oa);
        al[f] = *(const short8*)(pAlo + oa);
        const int ob = swz(wn + f * 16 + (l & 15), kb);
        bh[f] = *(const short8*)(pBhi + ob);
        bl[f] = *(const short8*)(pBlo + ob);
      }
#pragma unroll
      for (int fm = 0; fm < 4; ++fm)
#pragma unroll
        for (int fn = 0; fn < 4; ++fn) {
          acc[fm][fn] = __builtin_amdgcn_mfma_f32_16x16x32_bf16(ah[fm], bh[fn], acc[fm][fn], 0, 0, 0);
          acc[fm][fn] = __builtin_amdgcn_mfma_f32_16x16x32_bf16(al[fm], bh[fn], acc[fm][fn], 0, 0, 0);
          acc[fm][fn] = __builtin_amdgcn_mfma_f32_16x16x32_bf16(ah[fm], bl[fn], acc[fm][fn], 0, 0, 0);
        }
    }
  };

  load_stage(0);
  write_stage();
  __syncthreads();
  for (int s = 0; s < 15; ++s) {
    load_stage(s + 1);
    compute_stage();
    __syncthreads();
    write_stage();
    __syncthreads();
  }
  compute_stage();

  float bcol[4];
#pragma unroll
  for (int fn = 0; fn < 4; ++fn) bcol[fn] = bias[n0 + wn + fn * 16 + (l & 15)];
#pragma unroll
  for (int fm = 0; fm < 4; ++fm)
#pragma unroll
    for (int fn = 0; fn < 4; ++fn)
#pragma unroll
      for (int q = 0; q < 4; ++q)
        acc[fm][fn][q] = ftanh(acc[fm][fn][q] + bcol[fn]);

  unsigned short* ldsT = lds;  // reused as [128][136]
  const int rr = t >> 1, ch = (t & 1) * 64;
  __syncthreads();
#pragma unroll
  for (int fm = 0; fm < 4; ++fm)
#pragma unroll
    for (int fn = 0; fn < 4; ++fn)
#pragma unroll
      for (int q = 0; q < 4; ++q) {
        const int rl = wm + fm * 16 + (l >> 4) * 4 + q;
        const int cl = wn + fn * 16 + (l & 15);
        ldsT[rl * 136 + cl] = f2bf(acc[fm][fn][q]);
      }
  __syncthreads();
#pragma unroll
  for (int i = 0; i < 8; ++i) {
    uint4 v = *(const uint4*)(ldsT + rr * 136 + ch + i * 8);
    *(uint4*)(outHi + (size_t)(m0 + rr) * 1024 + n0 + ch + i * 8) = v;
  }
  __syncthreads();
#pragma unroll
  for (int fm = 0; fm < 4; ++fm)
#pragma unroll
    for (int fn = 0; fn < 4; ++fn)
#pragma unroll
      for (int q = 0; q < 4; ++q) {
        const int rl = wm + fm * 16 + (l >> 4) * 4 + q;
        const int cl = wn + fn * 16 + (l & 15);
        const float x = acc[fm][fn][q];
        const unsigned short hh = f2bf(x);
        ldsT[rl * 136 + cl] = f2bf(x - bf2f(hh));
      }
  __syncthreads();
#pragma unroll
  for (int i = 0; i < 8; ++i) {
    uint4 v = *(const uint4*)(ldsT + rr * 136 + ch + i * 8);
    *(uint4*)(outLo + (size_t)(m0 + rr) * 1024 + n0 + ch + i * 8) = v;
  }
}

// ---------------------------------------------------------------------------
// k_scores_mfma: scores = proj @ words^T (split-bf16 3-term), f32 -> ws.
// Linear grid 2048 with XCD-pinned swizzle (bijective, audited): all 64
// blocks of batch b on XCD b%8 so proj[b] stays L2-resident.
// ---------------------------------------------------------------------------
__global__ __launch_bounds__(256, 2) void k_scores_mfma(
    const unsigned short* __restrict__ pHi, const unsigned short* __restrict__ pLo,
    const float* __restrict__ words, float* __restrict__ sc) {
  __shared__ unsigned short lds[32768];
  char* const ldsb = (char*)lds;
  char* const pAhi = ldsb;
  char* const pAlo = ldsb + 16384;
  char* const pBhi = ldsb + 32768;
  char* const pBlo = ldsb + 49152;
  const int t = threadIdx.x, l = t & 63, wave = t >> 6;
  const int wm = (wave >> 1) * 64, wn = (wave & 1) * 64;
  const int g = blockIdx.x;
  const int xcd = g & 7;
  const int slot = g >> 3;            // 0..255
  const int b = xcd + 8 * (slot >> 6);
  const int inner = slot & 63;
  const int m0 = (inner & 3) * 128;
  const int n0 = (inner >> 2) * 128;
  const int mg = b * 512 + m0;
  const float* wB = words + (size_t)b * WN * D_;
  const int r = t >> 1, h = t & 1;

  f32x4 acc[4][4];
#pragma unroll
  for (int i = 0; i < 4; ++i)
#pragma unroll
    for (int j = 0; j < 4; ++j) acc[i][j] = (f32x4){0.f, 0.f, 0.f, 0.f};

  uint4 avh[4], avl[4];
  f32x4 br[8];

  auto load_stage = [&](int s) {
    const unsigned short* ah_ = pHi + (size_t)(mg + r) * 1024 + s * 64 + h * 32;
    const unsigned short* al_ = pLo + (size_t)(mg + r) * 1024 + s * 64 + h * 32;
#pragma unroll
    for (int i = 0; i < 4; ++i) {
      avh[i] = ((const uint4*)ah_)[i];
      avl[i] = ((const uint4*)al_)[i];
    }
    const float* bs = wB + (size_t)(n0 + r) * 1024 + s * 64 + h * 32;
#pragma unroll
    for (int i = 0; i < 8; ++i) br[i] = *(const f32x4*)(bs + i * 4);
  };

  auto write_stage = [&]() {
#pragma unroll
    for (int i = 0; i < 4; ++i) {
      const int o = swz(r, h * 64 + i * 16);
      *(uint4*)(pAhi + o) = avh[i];
      *(uint4*)(pAlo + o) = avl[i];
    }
    unsigned short hB[32], lB[32];
#pragma unroll
    for (int i = 0; i < 8; ++i)
#pragma unroll
      for (int j = 0; j < 4; ++j) {
        float y = br[i][j];
        unsigned short hb = f2bf(y);
        hB[i * 4 + j] = hb;
        lB[i * 4 + j] = f2bf(y - bf2f(hb));
      }
#pragma unroll
    for (int i = 0; i < 4; ++i) {
      const int o = swz(r, h * 64 + i * 16);
      *(uint4*)(pBhi + o) = pack8(hB[i*8+0],hB[i*8+1],hB[i*8+2],hB[i*8+3],hB[i*8+4],hB[i*8+5],hB[i*8+6],hB[i*8+7]);
      *(uint4*)(pBlo + o) = pack8(lB[i*8+0],lB[i*8+1],lB[i*8+2],lB[i*8+3],lB[i*8+4],lB[i*8+5],lB[i*8+6],lB[i*8+7]);
    }
  };

  auto compute_stage = [&]() {
#pragma unroll
    for (int ks = 0; ks < 2; ++ks) {
      short8 ah[4], al[4], bh[4], bl[4];
      const int kb = ks * 64 + (l >> 4) * 16;
#pragma unroll
      for (int f = 0; f < 4; ++f) {
        const int oa = swz(wm + f * 16 + (l & 15), kb);
        ah[f] = *(const short8*)(pAhi + oa);
        al[f] = *(const short8*)(pAlo + oa);
        const int ob = swz(wn + f * 16 + (l & 15), kb);
        bh[f] = *(const short8*)(pBhi + ob);
        bl[f] = *(const short8*)(pBlo + ob);
      }
#pragma unroll
      for (int fm = 0; fm < 4; ++fm)
#pragma unroll
        for (int fn = 0; fn < 4; ++fn) {
          acc[fm][fn] = __builtin_amdgcn_mfma_f32_16x16x32_bf16(ah[fm], bh[fn], acc[fm][fn], 0, 0, 0);
          acc[fm][fn] = __builtin_amdgcn_mfma_f32_16x16x32_bf16(al[fm], bh[fn], acc[fm][fn], 0, 0, 0);
          acc[fm][fn] = __builtin_amdgcn_mfma_f32_16x16x32_bf16(ah[fm], bl[fn], acc[fm][fn], 0, 0, 0);
        }
    }
  };

  load_stage(0);
  write_stage();
  __syncthreads();
  for (int s = 0; s < 15; ++s) {
    load_stage(s + 1);
    compute_stage();
    __syncthreads();
    write_stage();
    __syncthreads();
  }
  compute_stage();

#pragma unroll
  for (int fm = 0; fm < 4; ++fm)
#pragma unroll
    for (int fn = 0; fn < 4; ++fn)
#pragma unroll
      for (int q = 0; q < 4; ++q) {
        const int rl = wm + fm * 16 + (l >> 4) * 4 + q;
        const int cl = wn + fn * 16 + (l & 15);
        sc[((size_t)b * 512 + m0 + rl) * 2048 + n0 + cl] = acc[fm][fn][q];
      }
}

// ---------------------------------------------------------------------------
// k_softmax: unchanged (verified).
// ---------------------------------------------------------------------------
__global__ __launch_bounds__(256) void k_softmax(float* __restrict__ ws,
                                                 const void* __restrict__ mask) {
  __shared__ float red[8];
  const int row = blockIdx.x;
  const int t = threadIdx.x;
  const int wave = t >> 6;
  float* rp = ws + (size_t)row * 2048;
  float v[8];
  {
    f32x4 v0 = *(const f32x4*)(rp + t * 8);
    f32x4 v1 = *(const f32x4*)(rp + t * 8 + 4);
#pragma unroll
    for (int i = 0; i < 4; ++i) { v[i] = v0[i]; v[4 + i] = v1[i]; }
  }
  if (g_mask_is_int) {
    const int* mp = (const int*)mask + (size_t)row * 2048 + t * 8;
    const int4 m0 = *(const int4*)mp;
    const int4 m1 = *(const int4*)(mp + 4);
    if (m0.x) v[0] = -INFINITY;
    if (m0.y) v[1] = -INFINITY;
    if (m0.z) v[2] = -INFINITY;
    if (m0.w) v[3] = -INFINITY;
    if (m1.x) v[4] = -INFINITY;
    if (m1.y) v[5] = -INFINITY;
    if (m1.z) v[6] = -INFINITY;
    if (m1.w) v[7] = -INFINITY;
  } else {
    const unsigned char* mp = (const unsigned char*)mask + (size_t)row * 2048 + t * 8;
    const uchar4 m0 = *(const uchar4*)mp;
    const uchar4 m1 = *(const uchar4*)(mp + 4);
    if (m0.x) v[0] = -INFINITY;
    if (m0.y) v[1] = -INFINITY;
    if (m0.z) v[2] = -INFINITY;
    if (m0.w) v[3] = -INFINITY;
    if (m1.x) v[4] = -INFINITY;
    if (m1.y) v[5] = -INFINITY;
    if (m1.z) v[6] = -INFINITY;
    if (m1.w) v[7] = -INFINITY;
  }
  float mx = v[0];
#pragma unroll
  for (int i = 1; i < 8; ++i) mx = fmaxf(mx, v[i]);
#pragma unroll
  for (int off = 32; off > 0; off >>= 1) mx = fmaxf(mx, __shfl_xor(mx, off));
  if ((t & 63) == 0) red[wave] = mx;
  __syncthreads();
  mx = fmaxf(fmaxf(red[0], red[1]), fmaxf(red[2], red[3]));
  float e[8];
  float sum = 0.0f;
#pragma unroll
  for (int i = 0; i < 8; ++i) {
    e[i] = __expf(v[i] - mx);
    sum += e[i];
  }
#pragma unroll
  for (int off = 32; off > 0; off >>= 1) sum += __shfl_xor(sum, off);
  if ((t & 63) == 0) red[4 + wave] = sum;
  __syncthreads();
  const float tot = (red[4] + red[5]) + (red[6] + red[7]);
  const float rinv = 1.0f / tot;
  unsigned short* op = (unsigned short*)rp;
  ushort4 o0, o1;
  o0.x = f2bf(e[0] * rinv); o0.y = f2bf(e[1] * rinv);
  o0.z = f2bf(e[2] * rinv); o0.w = f2bf(e[3] * rinv);
  o1.x = f2bf(e[4] * rinv); o1.y = f2bf(e[5] * rinv);
  o1.z = f2bf(e[6] * rinv); o1.w = f2bf(e[7] * rinv);
  *(ushort4*)(op + t * 8) = o0;
  *(ushort4*)(op + t * 8 + 4) = o1;
}

// ---------------------------------------------------------------------------
// k_pv: ctx = att @ words. BM=512 (full E per block) x BW=128, K=2048.
// 256 blocks (b,w-tile), XCD-pinned: all 8 w-tiles of b on XCD b%8.
// 512 threads = 8 waves (4 m x 2 w). words read EXACTLY once from HBM.
// B staged transposed [w][n] bf16 via packed-u32 writes (round-3-verified
// pattern); fragments read with plain short8 + XOR swizzle. No asm.
// ---------------------------------------------------------------------------
__global__ __launch_bounds__(512, 2) void k_pv(
    const unsigned short* __restrict__ att, const float* __restrict__ words,
    float* __restrict__ out) {
  __shared__ uint4 lds4[5120];            // 80 KB: A 64KB | B 16KB
  char* const pA = (char*)lds4;
  char* const pB = (char*)lds4 + 65536;

  const int g = blockIdx.x;
  const int b = (g & 7) + 8 * (g >> 6);   // XCD-pinned batch
  const int wt = (g >> 3) & 7;
  const int w0 = wt * 128;

  const int t = threadIdx.x, l = t & 63, wv = t >> 6;
  const int wm4 = wv >> 1;    // 0..3 -> m base = wm4*128
  const int wn2 = wv & 1;     // 0..1 -> w base (local) = wn2*64

  f32x4 acc[8][4];
#pragma unroll
  for (int i = 0; i < 8; ++i)
#pragma unroll
    for (int j = 0; j < 4; ++j) acc[i][j] = (f32x4){0.f, 0.f, 0.f, 0.f};

  uint4 avA[8];
  f32x4 bv0a, bv0b, bv1a, bv1b;        // words rows np2, np2+1; 8 w each

  const int np2 = (t & 31) * 2;        // n-pair base within stage (0..62)
  const int wc = (t >> 5) * 8;         // w-chunk base (0..120)

  auto load_stage = [&](int s) {
    // A: att rows (t>>3)+i*64, 8-ushort chunk (t&7); row stride 4096 ushorts
    const unsigned short* ab =
        att + ((size_t)(b * 512) + (t >> 3)) * 4096 + s * 64 + (t & 7) * 8;
#pragma unroll
    for (int i = 0; i < 8; ++i)
      avA[i] = *(const uint4*)(ab + (size_t)i * 64 * 4096);
    // B: words rows n = s*64+np2, s*64+np2+1; cols w0+wc .. +8
    const float* wp = words + (size_t)b * WN * D_ +
                      (size_t)(s * 64 + np2) * 1024 + w0 + wc;
    bv0a = *(const f32x4*)(wp);
    bv0b = *(const f32x4*)(wp + 4);
    bv1a = *(const f32x4*)(wp + 1024);
    bv1b = *(const f32x4*)(wp + 1028);
  };

  auto write_stage = [&]() {
#pragma unroll
    for (int i = 0; i < 8; ++i) {
      const int row = (t >> 3) + i * 64;
      *(uint4*)(pA + row * 128 + (((t & 7) * 16) ^ ((row & 7) << 4))) = avA[i];
    }
    // B transposed: row w, u32 = (bf16[n=np2], bf16[n=np2+1])
#pragma unroll
    for (int i = 0; i < 8; ++i) {
      const int w = wc + i;
      const float x0 = (i < 4) ? bv0a[i & 3] : bv0b[i & 3];
      const float x1 = (i < 4) ? bv1a[i & 3] : bv1b[i & 3];
      const unsigned int pk =
          (unsigned int)f2bf(x0) | ((unsigned int)f2bf(x1) << 16);
      *(unsigned int*)(pB + w * 128 + ((np2 * 2) ^ ((w & 7) << 4))) = pk;
    }
  };

  auto compute_stage = [&]() {
#pragma unroll
    for (int ks = 0; ks < 2; ++ks) {
      short8 a[8];
      const int kb = ks * 64 + (l >> 4) * 16;
#pragma unroll
      for (int f = 0; f < 8; ++f) {
        const int row = wm4 * 128 + f * 16 + (l & 15);
        a[f] = *(const short8*)(pA + swz(row, kb));
      }
      short8 bb[4];
#pragma unroll
      for (int f = 0; f < 4; ++f) {
        const int row = wn2 * 64 + f * 16 + (l & 15);
        bb[f] = *(const short8*)(pB + swz(row, kb));
      }
#pragma unroll
      for (int fm = 0; fm < 8; ++fm)
#pragma unroll
        for (int fn = 0; fn < 4; ++fn)
          acc[fm][fn] = __builtin_amdgcn_mfma_f32_16x16x32_bf16(a[fm], bb[fn], acc[fm][fn], 0, 0, 0);
    }
  };

  load_stage(0);
  for (int s = 0; s < 32; ++s) {
    __syncthreads();           // previous compute done; LDS writable
    write_stage();
    __syncthreads();
    if (s < 31) load_stage(s + 1);
    compute_stage();
  }

  // epilogue: scattered f32 stores (64B row segments)
#pragma unroll
  for (int fm = 0; fm < 8; ++fm)
#pragma unroll
    for (int fn = 0; fn < 4; ++fn)
#pragma unroll
      for (int q = 0; q < 4; ++q) {
        const int row = wm4 * 128 + fm * 16 + (l >> 4) * 4 + q;
        const int col = w0 + wn2 * 64 + fn * 16 + (l & 15);
        out[((size_t)b * 512 + row) * 1024 + col] = acc[fm][fn][q];
      }
}

// ===========================================================================
// FALLBACK PATH (round-2 verified kernels; used if ws too small)
// ===========================================================================
__global__ __launch_bounds__(256, 4) void k_proj(const float* __restrict__ A,
                                                 const float* __restrict__ W,
                                                 const float* __restrict__ bias,
                                                 float* __restrict__ out) {
  __shared__ float As[32][132];
  __shared__ float Bs[32][132];
  const int t = threadIdx.x;
  const int m0 = blockIdx.x * 128;
  const int n0 = blockIdx.y * 128;
  const int tm = t >> 4;
  const int tn = t & 15;
  const int lrow = t >> 1;
  const int lk = (t & 1) * 16;

  float acc[8][8];
#pragma unroll
  for (int i = 0; i < 8; ++i)
#pragma unroll
    for (int j = 0; j < 8; ++j) acc[i][j] = 0.0f;

  const float* Arow = A + (size_t)(m0 + lrow) * D_ + lk;
  const float* Wrow = W + (size_t)(n0 + lrow) * D_ + lk;

  for (int k0 = 0; k0 < D_; k0 += 32) {
    __syncthreads();
#pragma unroll
    for (int j = 0; j < 4; ++j) {
      const float4 va = *(const float4*)(Arow + k0 + j * 4);
      As[lk + j * 4 + 0][lrow] = va.x;
      As[lk + j * 4 + 1][lrow] = va.y;
      As[lk + j * 4 + 2][lrow] = va.z;
      As[lk + j * 4 + 3][lrow] = va.w;
      const float4 vb = *(const float4*)(Wrow + k0 + j * 4);
      Bs[lk + j * 4 + 0][lrow] = vb.x;
      Bs[lk + j * 4 + 1][lrow] = vb.y;
      Bs[lk + j * 4 + 2][lrow] = vb.z;
      Bs[lk + j * 4 + 3][lrow] = vb.w;
    }
    __syncthreads();
#pragma unroll 8
    for (int k = 0; k < 32; ++k) {
      float a[8], bb[8];
      *(float4*)(a + 0) = *(const float4*)&As[k][tm * 4];
      *(float4*)(a + 4) = *(const float4*)&As[k][tm * 4 + 64];
      *(float4*)(bb + 0) = *(const float4*)&Bs[k][tn * 4];
      *(float4*)(bb + 4) = *(const float4*)&Bs[k][tn * 4 + 64];
#pragma unroll
      for (int i = 0; i < 8; ++i)
#pragma unroll
        for (int j = 0; j < 8; ++j) acc[i][j] = fmaf(a[i], bb[j], acc[i][j]);
    }
  }

  float bn[8];
#pragma unroll
  for (int j = 0; j < 8; ++j) bn[j] = bias[n0 + tn * 4 + (j & 3) + (j >> 2) * 64];
#pragma unroll
  for (int i = 0; i < 8; ++i) {
    const int m = m0 + tm * 4 + (i & 3) + (i >> 2) * 64;
    float4 v0, v1;
    v0.x = tanhf(acc[i][0] + bn[0]);
    v0.y = tanhf(acc[i][1] + bn[1]);
    v0.z = tanhf(acc[i][2] + bn[2]);
    v0.w = tanhf(acc[i][3] + bn[3]);
    v1.x = tanhf(acc[i][4] + bn[4]);
    v1.y = tanhf(acc[i][5] + bn[5]);
    v1.z = tanhf(acc[i][6] + bn[6]);
    v1.w = tanhf(acc[i][7] + bn[7]);
    *(float4*)(out + (size_t)m * D_ + n0 + tn * 4) = v0;
    *(float4*)(out + (size_t)m * D_ + n0 + tn * 4 + 64) = v1;
  }
}

__global__ __launch_bounds__(256) void k_scores(const float* __restrict__ words,
                                                const void* __restrict__ mask,
                                                float* __restrict__ pa) {
  __shared__ float Pt[1024][18];
  __shared__ float Ws[64][268];
  const int t = threadIdx.x;
  const int b = blockIdx.x >> 5;
  const int et = blockIdx.x & 31;
  const int e0 = et * 16;
  const int eg = t >> 5;
  const int ng = t & 31;
  const int mask_is_int = g_mask_is_int;
  const float* wbase = words + (size_t)b * WN * D_;

  {
    const int row = t >> 4;
    const int dj = (t & 15) * 4;
    const float* pr = pa + (size_t)(b * E_ + e0 + row) * D_;
#pragma unroll
    for (int rr = 0; rr < 16; ++rr) {
      const float4 v = *(const float4*)(pr + dj + rr * 64);
      Pt[dj + rr * 64 + 0][row] = v.x;
      Pt[dj + rr * 64 + 1][row] = v.y;
      Pt[dj + rr * 64 + 2][row] = v.z;
      Pt[dj + rr * 64 + 3][row] = v.w;
    }
  }

  float s[2][64];
#pragma unroll
  for (int i = 0; i < 2; ++i)
#pragma unroll
    for (int u = 0; u < 64; ++u) s[i][u] = 0.0f;

  const int nl = t >> 3;
  const int d4 = (t & 7) * 4;

  for (int dk = 0; dk < D_; dk += 64) {
#pragma unroll
    for (int nb = 0; nb < 8; ++nb) {
      __syncthreads();
#pragma unroll
      for (int rr = 0; rr < 8; ++rr) {
#pragma unroll
        for (int hh = 0; hh < 2; ++hh) {
          const int n = nl + rr * 32;
          const int d = d4 + hh * 32;
          const float4 v = *(const float4*)(wbase + (size_t)(nb * 256 + n) * D_ + dk + d);
          Ws[d + 0][n] = v.x;
          Ws[d + 1][n] = v.y;
          Ws[d + 2][n] = v.z;
          Ws[d + 3][n] = v.w;
        }
      }
      __syncthreads();
#pragma unroll 2
      for (int k = 0; k < 64; ++k) {
        const float2 a = *(const float2*)&Pt[dk + k][eg * 2];
        const float4 b0 = *(const float4*)&Ws[k][ng * 4];
        const float4 b1 = *(const float4*)&Ws[k][128 + ng * 4];
        const float aa[2] = {a.x, a.y};
        const float bb[8] = {b0.x, b0.y, b0.z, b0.w, b1.x, b1.y, b1.z, b1.w};
#pragma unroll
        for (int i = 0; i < 2; ++i)
#pragma unroll
          for (int u = 0; u < 8; ++u)
            s[i][nb * 8 + u] = fmaf(aa[i], bb[u], s[i][nb * 8 + u]);
      }
    }
  }

#pragma unroll
  for (int i = 0; i < 2; ++i) {
    const int e = e0 + eg * 2 + i;
#pragma unroll
    for (int nb = 0; nb < 8; ++nb)
#pragma unroll
      for (int q = 0; q < 2; ++q) {
        const size_t moff = (size_t)(b * E_ + e) * WN + nb * 256 + q * 128 + ng * 4;
        int mx, my, mz, mw;
        if (mask_is_int) {
          const int4 mv = *(const int4*)((const int*)mask + moff);
          mx = mv.x; my = mv.y; mz = mv.z; mw = mv.w;
        } else {
          const uchar4 mv = *(const uchar4*)((const unsigned char*)mask + moff);
          mx = mv.x; my = mv.y; mz = mv.z; mw = mv.w;
        }
        if (mx) s[i][nb * 8 + q * 4 + 0] = -1e30f;
        if (my) s[i][nb * 8 + q * 4 + 1] = -1e30f;
        if (mz) s[i][nb * 8 + q * 4 + 2] = -1e30f;
        if (mw) s[i][nb * 8 + q * 4 + 3] = -1e30f;
      }
    float m = -1e30f;
#pragma unroll
    for (int u = 0; u < 64; ++u) m = fmaxf(m, s[i][u]);
#pragma unroll
    for (int off = 16; off > 0; off >>= 1) m = fmaxf(m, __shfl_xor(m, off));
    float sum = 0.0f;
#pragma unroll
    for (int u = 0; u < 64; ++u) {
      const float p = __expf(s[i][u] - m);
      s[i][u] = p;
      sum += p;
    }
#pragma unroll
    for (int off = 16; off > 0; off >>= 1) sum += __shfl_xor(sum, off);
    const float rinv = 1.0f / sum;

    unsigned short* ar2 = (unsigned short*)(pa + (size_t)(b * E_ + e) * WN / 2);
#pragma unroll
    for (int nb = 0; nb < 8; ++nb)
#pragma unroll
      for (int q = 0; q < 2; ++q) {
        ushort4 pk;
        pk.x = f2bf(s[i][nb * 8 + q * 4 + 0] * rinv);
        pk.y = f2bf(s[i][nb * 8 + q * 4 + 1] * rinv);
        pk.z = f2bf(s[i][nb * 8 + q * 4 + 2] * rinv);
        pk.w = f2bf(s[i][nb * 8 + q * 4 + 3] * rinv);
        *(ushort4*)(ar2 + nb * 256 + q * 128 + ng * 4) = pk;
      }
  }
}

__global__ __launch_bounds__(256) void k_ctx(const float* __restrict__ words,
                                             float* __restrict__ pa) {
  __shared__ unsigned short att_s[16][2048];
  __shared__ unsigned short Wb[256][132];
  const int t = threadIdx.x;
  const int b = blockIdx.x >> 5;
  const int et = blockIdx.x & 31;
  const int e0 = et * 16;
  const int eg = t >> 5;
  const int wg = t & 31;
  const float* wbase = words + (size_t)b * WN * D_;

  {
    const int row = t >> 4;
    const int cj = t & 15;
    const uint4* pr = (const uint4*)(pa + (size_t)(b * E_ + e0 + row) * D_);
#pragma unroll
    for (int rr = 0; rr < 16; ++rr) {
      const int c = cj + rr * 16;
      const uint4 v = pr[c];
      *(uint4*)&att_s[row][c * 8] = v;
    }
  }

  float acc[2][32];
#pragma unroll
  for (int i = 0; i < 2; ++i)
#pragma unroll
    for (int u = 0; u < 32; ++u) acc[i][u] = 0.0f;

  const int nlg = t >> 5;
  const int w4 = (t & 31) * 4;

  for (int nb = 0; nb < 8; ++nb) {
#pragma unroll
    for (int q = 0; q < 8; ++q) {
      __syncthreads();
#pragma unroll
      for (int rr = 0; rr < 32; ++rr) {
        const int n = nlg + rr * 8;
        const float4 v = *(const float4*)(wbase + (size_t)(nb * 256 + n) * D_ + q * 128 + w4);
        ushort4 pk;
        pk.x = f2bf(v.x);
        pk.y = f2bf(v.y);
        pk.z = f2bf(v.z);
        pk.w = f2bf(v.w);
        *(ushort4*)&Wb[n][w4] = pk;
      }
      __syncthreads();
#pragma unroll 4
      for (int n2 = 0; n2 < 128; ++n2) {
        const int n = n2 * 2;
        const ushort4 r0 = *(const ushort4*)&Wb[n][wg * 4];
        const ushort4 r1 = *(const ushort4*)&Wb[n + 1][wg * 4];
        const float w0[4] = {bf2f(r0.x), bf2f(r0.y), bf2f(r0.z), bf2f(r0.w)};
        const float w1[4] = {bf2f(r1.x), bf2f(r1.y), bf2f(r1.z), bf2f(r1.w)};
#pragma unroll
        for (int i = 0; i < 2; ++i) {
          const unsigned int aw = *(const unsigned int*)&att_s[eg * 2 + i][nb * 256 + n];
          const float a0 = bf2f((unsigned short)(aw & 0xffffu));
          const float a1 = bf2f((unsigned short)(aw >> 16));
#pragma unroll
          for (int j = 0; j < 4; ++j)
            acc[i][q * 4 + j] = fmaf(a0, w0[j], fmaf(a1, w1[j], acc[i][q * 4 + j]));
        }
      }
    }
  }

#pragma unroll
  for (int i = 0; i < 2; ++i) {
    float* orow = pa + (size_t)(b * E_ + e0 + eg * 2 + i) * D_;
#pragma unroll
    for (int q = 0; q < 8; ++q) {
      float4 v;
      v.x = acc[i][q * 4 + 0];
      v.y = acc[i][q * 4 + 1];
      v.z = acc[i][q * 4 + 2];
      v.w = acc[i][q * 4 + 3];
      *(float4*)(orow + q * 128 + wg * 4) = v;
    }
  }
}

extern "C" void kernel_launch(void* const* d_in, const int* in_sizes, int n_in,
                              void* d_out, int out_size, void* d_ws, size_t ws_size,
                              hipStream_t stream) {
  const float* ems = (const float*)d_in[0];
  const float* words = (const float*)d_in[1];
  const void* mask = d_in[2];
  const float* w_weight = (const float*)d_in[3];
  const float* w_bias = (const float*)d_in[4];

  k_detect<<<1, 64, 0, stream>>>((const unsigned char*)mask);

  const size_t ws_need = (size_t)16384 * 2048 * 4;
  if (ws_size >= ws_need) {
    unsigned short* hiP = (unsigned short*)d_out;
    unsigned short* loP = hiP + (size_t)16384 * 1024;
    float* ws = (float*)d_ws;
    k_proj_mfma<<<dim3(128, 8), 256, 0, stream>>>(ems, w_weight, w_bias, hiP, loP);
    k_scores_mfma<<<dim3(2048), 256, 0, stream>>>(hiP, loP, words, ws);
    k_softmax<<<dim3(16384), 256, 0, stream>>>(ws, mask);
    k_pv<<<dim3(256), 512, 0, stream>>>((const unsigned short*)d_ws, words,
                                        (float*)d_out);
  } else {
    float* out = (float*)d_out;
    k_proj<<<dim3(128, 8), 256, 0, stream>>>(ems, w_weight, w_bias, out);
    k_scores<<<dim3(B_ * (E_ / 16)), 256, 0, stream>>>(words, mask, out);
    k_ctx<<<dim3(B_ * (E_ / 16)), 256, 0, stream>>>(words, out);
  }
}